// Round 12
// baseline (166.070 us; speedup 1.0000x reference)
//
#include <hip/hip_runtime.h>
#include <hip/hip_bf16.h>

#define N_NODES 50000
#define N_EDGES 800000
#define IN_DIM 128
#define OUT_DIM 64
#define NEG_SLOPE 0.01f
#define NEG_INF (-3.0e38f)

#define N_STRIPS (N_NODES / 16)       // 3125 16-node MFMA strips
#define Z_BLOCKS ((N_STRIPS + 3) / 4) // 782 (4 waves/block, 1 strip/wave)
#define E_I4 (N_EDGES / 4)            // 200000 int4 edge groups

// bucket sort: 64 nodes/bucket -> bucket == one build_agg block
#define B_NODES 64
#define NB ((N_NODES + B_NODES - 1) / B_NODES)  // 782 buckets
#define CAP_B 1600                     // slab capacity (mean 1023, ~18 sigma)
#define CNT_STRIDE 16                  // 64B line per bucket cursor
#define EB 100                         // edge blocks
#define CHUNK_I4 (E_I4 / EB)           // 2000 int4 = 8000 edges per block

typedef __bf16 bf16x8 __attribute__((ext_vector_type(8)));
typedef float f32x4 __attribute__((ext_vector_type(4)));

__device__ __forceinline__ unsigned short f2bf_us(float f) {
  __hip_bfloat16 h = __float2bfloat16(f);  // RNE
  return *reinterpret_cast<unsigned short*>(&h);
}
__device__ __forceinline__ bf16x8 pack_bf16(float4 lo, float4 hi) {
  union { bf16x8 v; unsigned short u[8]; } r;
  r.u[0] = f2bf_us(lo.x); r.u[1] = f2bf_us(lo.y);
  r.u[2] = f2bf_us(lo.z); r.u[3] = f2bf_us(lo.w);
  r.u[4] = f2bf_us(hi.x); r.u[5] = f2bf_us(hi.y);
  r.u[6] = f2bf_us(hi.z); r.u[7] = f2bf_us(hi.w);
  return r.v;
}
__device__ __forceinline__ float bflo(unsigned u) {
  return __uint_as_float(u << 16);
}
__device__ __forceinline__ float bfhi(unsigned u) {
  return __uint_as_float(u & 0xffff0000u);
}

// ---------------------------------------------------------------------------
// Stage 1 (fused). Blocks [0, Z_BLOCKS): MFMA z-GEMM (R7 structure).
// Blocks [Z_BLOCKS,...): bucket pass — LDS count per 64-node bucket ->
// one reserve atomic per (block,bucket) -> place packed (localdst<<16|src).
// ---------------------------------------------------------------------------
__global__ __launch_bounds__(256) void gat_z_bucket(
    const float* __restrict__ feat, const float* __restrict__ fcw,
    const float* __restrict__ attnw, __hip_bfloat16* __restrict__ z,
    float* __restrict__ asrc, float* __restrict__ adst,
    const int* __restrict__ src, const int* __restrict__ dst,
    int* __restrict__ cnt, unsigned* __restrict__ pairs) {
  if (blockIdx.x >= Z_BLOCKS) {
    __shared__ int hist[NB];
    __shared__ int curs[NB];
    const int tid = threadIdx.x;
    const int i0 = (blockIdx.x - Z_BLOCKS) * CHUNK_I4;
    for (int i = tid; i < NB; i += 256) hist[i] = 0;
    __syncthreads();
    for (int t = i0 + tid; t < i0 + CHUNK_I4; t += 256) {
      int4 d = ((const int4*)dst)[t];
      atomicAdd(&hist[d.x >> 6], 1);
      atomicAdd(&hist[d.y >> 6], 1);
      atomicAdd(&hist[d.z >> 6], 1);
      atomicAdd(&hist[d.w >> 6], 1);
    }
    __syncthreads();
    for (int i = tid; i < NB; i += 256) {
      int h = hist[i];
      curs[i] = h ? atomicAdd(cnt + i * CNT_STRIDE, h) : 0;
    }
    __syncthreads();
    for (int t = i0 + tid; t < i0 + CHUNK_I4; t += 256) {
      int4 s = ((const int4*)src)[t];
      int4 d = ((const int4*)dst)[t];
#define BKT_PUT(dd, ss)                                                    \
  {                                                                        \
    int b = (dd) >> 6;                                                     \
    int r = atomicAdd(&curs[b], 1);                                        \
    if (r < CAP_B)                                                         \
      pairs[(size_t)b * CAP_B + r] =                                       \
          ((unsigned)((dd) & 63) << 16) | (unsigned)(ss);                  \
  }
      BKT_PUT(d.x, s.x)
      BKT_PUT(d.y, s.y)
      BKT_PUT(d.z, s.z)
      BKT_PUT(d.w, s.w)
#undef BKT_PUT
    }
    return;
  }

  const int lane = threadIdx.x & 63;
  const int m = lane & 15;
  const int quad = lane >> 4;
  const int wv = blockIdx.x * 4 + (threadIdx.x >> 6);
  if (wv >= N_STRIPS) return;
  const int n0 = wv * 16;

  bf16x8 bfrag[4][4];
#pragma unroll
  for (int t = 0; t < 4; ++t) {
    const float* wr = fcw + (size_t)(m + 16 * t) * IN_DIM + quad * 8;
#pragma unroll
    for (int c = 0; c < 4; ++c) {
      float4 lo = *(const float4*)(wr + c * 32);
      float4 hi = *(const float4*)(wr + c * 32 + 4);
      bfrag[t][c] = pack_bf16(lo, hi);
    }
  }

  f32x4 acc[4] = {{0.f, 0.f, 0.f, 0.f}, {0.f, 0.f, 0.f, 0.f},
                  {0.f, 0.f, 0.f, 0.f}, {0.f, 0.f, 0.f, 0.f}};
  const float* ar = feat + (size_t)(n0 + m) * IN_DIM + quad * 8;
#pragma unroll
  for (int c = 0; c < 4; ++c) {
    float4 lo = *(const float4*)(ar + c * 32);
    float4 hi = *(const float4*)(ar + c * 32 + 4);
    const bf16x8 af = pack_bf16(lo, hi);
#pragma unroll
    for (int t = 0; t < 4; ++t)
      acc[t] = __builtin_amdgcn_mfma_f32_16x16x32_bf16(af, bfrag[t][c],
                                                       acc[t], 0, 0, 0);
  }

#pragma unroll
  for (int t = 0; t < 4; ++t)
#pragma unroll
    for (int r = 0; r < 4; ++r)
      z[(size_t)(n0 + quad * 4 + r) * OUT_DIM + m + 16 * t] =
          __float2bfloat16(acc[t][r]);

  float aws[4], awd[4];
#pragma unroll
  for (int t = 0; t < 4; ++t) {
    aws[t] = attnw[m + 16 * t];
    awd[t] = attnw[OUT_DIM + m + 16 * t];
  }
  float ps[4], pd[4];
#pragma unroll
  for (int r = 0; r < 4; ++r) {
    float s = 0.f, d = 0.f;
#pragma unroll
    for (int t = 0; t < 4; ++t) {
      s = fmaf(acc[t][r], aws[t], s);
      d = fmaf(acc[t][r], awd[t], d);
    }
    ps[r] = s;
    pd[r] = d;
  }
#pragma unroll
  for (int off = 1; off < 16; off <<= 1) {
#pragma unroll
    for (int r = 0; r < 4; ++r) {
      ps[r] += __shfl_xor(ps[r], off, 64);
      pd[r] += __shfl_xor(pd[r], off, 64);
    }
  }
  if (m == 0) {
#pragma unroll
    for (int r = 0; r < 4; ++r) {
      asrc[n0 + quad * 4 + r] = ps[r];
      adst[n0 + quad * 4 + r] = pd[r];
    }
  }
}

// ---------------------------------------------------------------------------
// Fused CSR-build + aggregation. One block per 64-node bucket:
//  1. LDS hist (64 bins) over the bucket's pairs slab; wave-0 shfl scan.
//  2. Place src into LDS lsorted (ushort) via LDS cursors.
//  3. Block-wide pre-gather avs[i] = asrc[lsorted[i]].
//  4. Each wave aggregates 16 nodes: exact 2-pass softmax from LDS,
//     (eg,j)-lane uint4 z gather + 8 FMAs, shfl reduce, fused ELU store.
// No global offsets/ssorted arrays; edge data never leaves the CU.
// ---------------------------------------------------------------------------
__global__ __launch_bounds__(256) void gat_build_agg(
    const unsigned* __restrict__ pairs, const int* __restrict__ cnt,
    const float* __restrict__ asrc, const float* __restrict__ adst,
    const __hip_bfloat16* __restrict__ zb, float* __restrict__ out) {
  __shared__ int hist[B_NODES], exo[B_NODES], cur[B_NODES];
  __shared__ unsigned short lsorted[CAP_B];
  __shared__ float avs[CAP_B];
  __shared__ float adl[B_NODES];
  const int b = blockIdx.x;
  const int tid = threadIdx.x;
  const int lane = tid & 63;
  const int wv = tid >> 6;

  if (tid < B_NODES) {
    hist[tid] = 0;
    const int node = b * B_NODES + tid;
    adl[tid] = (node < N_NODES) ? adst[node] : 0.f;
  }
  __syncthreads();

  const int c = min(cnt[b * CNT_STRIDE], CAP_B);
  const unsigned* bp = pairs + (size_t)b * CAP_B;
  for (int i = tid; i < c; i += 256) atomicAdd(&hist[bp[i] >> 16], 1);
  __syncthreads();

  if (wv == 0) {  // exclusive scan of 64 bins, one wave
    const int v = hist[lane];
    int incl = v;
#pragma unroll
    for (int off = 1; off < 64; off <<= 1) {
      int u = __shfl_up(incl, off, 64);
      if (lane >= off) incl += u;
    }
    exo[lane] = incl - v;
    cur[lane] = incl - v;
  }
  __syncthreads();

  for (int i = tid; i < c; i += 256) {
    const unsigned p = bp[i];
    const int r = atomicAdd(&cur[p >> 16], 1);
    lsorted[r] = (unsigned short)(p & 0xFFFFu);
  }
  __syncthreads();

  for (int i = tid; i < c; i += 256) avs[i] = asrc[lsorted[i]];
  __syncthreads();

  const uint4* __restrict__ zp4 = (const uint4*)zb;  // 8 uint4 per z row
  const int j = lane & 7;    // column quad: cols 8j..8j+7
  const int eg = lane >> 3;  // edge subgroup 0..7

#pragma unroll 1
  for (int it = 0; it < 16; ++it) {
    const int ln = 4 * it + wv;
    const int node = b * B_NODES + ln;
    if (node >= N_NODES) continue;  // wave-uniform
    const int base = exo[ln];
    const int cn = hist[ln];
    float4* __restrict__ orow = (float4*)(out + (size_t)node * OUT_DIM);
    if (cn == 0) {  // elu(0/1) = 0
      if (eg == 0) {
        const float4 zv = {0.f, 0.f, 0.f, 0.f};
        orow[2 * j] = zv;
        orow[2 * j + 1] = zv;
      }
      continue;
    }
    const float ad = adl[ln];

    // pass 1: ev = leaky(av + ad), exact max
    float m = NEG_INF;
    for (int e0 = 0; e0 < cn; e0 += 64) {
      const int e = e0 + lane;
      float ev = NEG_INF;
      if (e < cn) {
        const float v = avs[base + e] + ad;
        ev = v > 0.f ? v : NEG_SLOPE * v;
        avs[base + e] = ev;
      }
#pragma unroll
      for (int off = 32; off; off >>= 1)
        ev = fmaxf(ev, __shfl_xor(ev, off, 64));
      m = fmaxf(m, ev);
    }
    // pass 2: w = exp(ev - m), denom
    float dsum = 0.f;
    for (int e0 = 0; e0 < cn; e0 += 64) {
      const int e = e0 + lane;
      float w = 0.f;
      if (e < cn) {
        w = __expf(avs[base + e] - m);
        avs[base + e] = w;
      }
      dsum += w;
    }
#pragma unroll
    for (int off = 32; off; off >>= 1) dsum += __shfl_xor(dsum, off, 64);

    // gather: 8 edges per iteration, lane (eg,j) does edge e0+eg, cols 8j..
    float acc[8] = {0.f, 0.f, 0.f, 0.f, 0.f, 0.f, 0.f, 0.f};
    for (int e0 = 0; e0 < cn; e0 += 8) {
      const int e = e0 + eg;
      float w = 0.f;
      int s = 0;
      if (e < cn) {
        w = avs[base + e];
        s = lsorted[base + e];
      }
      const uint4 u = zp4[(size_t)s * 8 + j];  // w=0 for idle -> harmless
      acc[0] = fmaf(w, bflo(u.x), acc[0]);
      acc[1] = fmaf(w, bfhi(u.x), acc[1]);
      acc[2] = fmaf(w, bflo(u.y), acc[2]);
      acc[3] = fmaf(w, bfhi(u.y), acc[3]);
      acc[4] = fmaf(w, bflo(u.z), acc[4]);
      acc[5] = fmaf(w, bfhi(u.z), acc[5]);
      acc[6] = fmaf(w, bflo(u.w), acc[6]);
      acc[7] = fmaf(w, bfhi(u.w), acc[7]);
    }
#pragma unroll
    for (int off = 8; off < 64; off <<= 1)
#pragma unroll
      for (int c8 = 0; c8 < 8; ++c8) acc[c8] += __shfl_xor(acc[c8], off, 64);

    if (eg == 0) {
      const float inv = 1.f / (dsum > 0.f ? dsum : 1.f);
      float4 r0, r1;
      float h;
      h = acc[0] * inv; r0.x = h > 0.f ? h : expm1f(h);
      h = acc[1] * inv; r0.y = h > 0.f ? h : expm1f(h);
      h = acc[2] * inv; r0.z = h > 0.f ? h : expm1f(h);
      h = acc[3] * inv; r0.w = h > 0.f ? h : expm1f(h);
      h = acc[4] * inv; r1.x = h > 0.f ? h : expm1f(h);
      h = acc[5] * inv; r1.y = h > 0.f ? h : expm1f(h);
      h = acc[6] * inv; r1.z = h > 0.f ? h : expm1f(h);
      h = acc[7] * inv; r1.w = h > 0.f ? h : expm1f(h);
      orow[2 * j] = r0;
      orow[2 * j + 1] = r1;
    }
  }
}

// ---------------------------------------------------------------------------
extern "C" void kernel_launch(void* const* d_in, const int* in_sizes, int n_in,
                              void* d_out, int out_size, void* d_ws, size_t ws_size,
                              hipStream_t stream) {
  const float* feat  = (const float*)d_in[0];
  const float* fcw   = (const float*)d_in[1];
  const float* attnw = (const float*)d_in[2];
  const int* src     = (const int*)d_in[3];
  const int* dst     = (const int*)d_in[4];
  float* out = (float*)d_out;

  char* ws = (char*)d_ws;
  __hip_bfloat16* z = (__hip_bfloat16*)ws;
  ws += (size_t)N_NODES * OUT_DIM * sizeof(__hip_bfloat16);  // 6.4 MB
  float* asrc = (float*)ws;   ws += (size_t)N_NODES * sizeof(float);
  float* adst = (float*)ws;   ws += (size_t)N_NODES * sizeof(float);
  int* cnt = (int*)ws;        ws += (size_t)NB * CNT_STRIDE * sizeof(int);  // 50 KB
  unsigned* pairs = (unsigned*)ws; ws += (size_t)NB * CAP_B * sizeof(unsigned);  // 5.0 MB

  hipMemsetAsync(cnt, 0, (size_t)NB * CNT_STRIDE * sizeof(int), stream);

  gat_z_bucket<<<Z_BLOCKS + EB, 256, 0, stream>>>(
      feat, fcw, attnw, z, asrc, adst, src, dst, cnt, pairs);
  gat_build_agg<<<NB, 256, 0, stream>>>(pairs, cnt, asrc, adst, z, out);
}

// Round 13
// 150.975 us; speedup vs baseline: 1.1000x; 1.1000x over previous
//
#include <hip/hip_runtime.h>
#include <hip/hip_bf16.h>
#include <hip/hip_fp16.h>

#define N_NODES 50000
#define N_EDGES 800000
#define IN_DIM 128
#define OUT_DIM 64
#define NEG_SLOPE 0.01f
#define NEG_INF (-3.0e38f)

#define N_STRIPS (N_NODES / 16)       // 3125 16-node MFMA strips
#define Z_BLOCKS ((N_STRIPS + 3) / 4) // 782 (4 waves/block, 1 strip/wave)
#define E_I4 (N_EDGES / 4)            // 200000 int4 edge groups

// bucket sort: 128 nodes/bucket; block-local count -> reserve -> place
#define NB ((N_NODES + 127) / 128)    // 391 buckets
#define CAP_B 3072                     // slab capacity (mean occupancy 2046)
#define CNT_STRIDE 16                  // 64B line per bucket cursor
#define EB 250                         // edge blocks (was 100: 0.4 blk/CU was the
                                       // bucket-phase parallelism bottleneck)
#define CHUNK_I4 (E_I4 / EB)           // 800 int4 = 3200 edges per block

typedef __bf16 bf16x8 __attribute__((ext_vector_type(8)));
typedef float f32x4 __attribute__((ext_vector_type(4)));

__device__ __forceinline__ unsigned short f2bf_us(float f) {
  __hip_bfloat16 h = __float2bfloat16(f);  // RNE
  return *reinterpret_cast<unsigned short*>(&h);
}
__device__ __forceinline__ bf16x8 pack_bf16(float4 lo, float4 hi) {
  union { bf16x8 v; unsigned short u[8]; } r;
  r.u[0] = f2bf_us(lo.x); r.u[1] = f2bf_us(lo.y);
  r.u[2] = f2bf_us(lo.z); r.u[3] = f2bf_us(lo.w);
  r.u[4] = f2bf_us(hi.x); r.u[5] = f2bf_us(hi.y);
  r.u[6] = f2bf_us(hi.z); r.u[7] = f2bf_us(hi.w);
  return r.v;
}
__device__ __forceinline__ float bflo(unsigned u) {
  return __uint_as_float(u << 16);
}
__device__ __forceinline__ float bfhi(unsigned u) {
  return __uint_as_float(u & 0xffff0000u);
}

// ---------------------------------------------------------------------------
// Stage 1 (fused). Blocks [0, Z_BLOCKS): MFMA z-GEMM (R7 structure).
// Blocks [Z_BLOCKS,...): bucket pass (no per-edge global atomics:
// LDS count -> one reserve atomic per (block,bucket) -> place).
// ---------------------------------------------------------------------------
__global__ __launch_bounds__(256) void gat_z_bucket(
    const float* __restrict__ feat, const float* __restrict__ fcw,
    const float* __restrict__ attnw, __hip_bfloat16* __restrict__ z,
    float* __restrict__ asrc, float* __restrict__ adst,
    const int* __restrict__ src, const int* __restrict__ dst,
    int* __restrict__ cnt, unsigned* __restrict__ pairs) {
  if (blockIdx.x >= Z_BLOCKS) {
    __shared__ int hist[NB];
    __shared__ int curs[NB];
    const int tid = threadIdx.x;
    const int i0 = (blockIdx.x - Z_BLOCKS) * CHUNK_I4;
    for (int i = tid; i < NB; i += 256) hist[i] = 0;
    __syncthreads();
    for (int t = i0 + tid; t < i0 + CHUNK_I4; t += 256) {
      int4 d = ((const int4*)dst)[t];
      atomicAdd(&hist[d.x >> 7], 1);
      atomicAdd(&hist[d.y >> 7], 1);
      atomicAdd(&hist[d.z >> 7], 1);
      atomicAdd(&hist[d.w >> 7], 1);
    }
    __syncthreads();
    for (int i = tid; i < NB; i += 256) {
      int h = hist[i];
      curs[i] = h ? atomicAdd(cnt + i * CNT_STRIDE, h) : 0;
    }
    __syncthreads();
    for (int t = i0 + tid; t < i0 + CHUNK_I4; t += 256) {
      int4 s = ((const int4*)src)[t];
      int4 d = ((const int4*)dst)[t];
#define BKT_PUT(dd, ss)                                                    \
  {                                                                        \
    int b = (dd) >> 7;                                                     \
    int r = atomicAdd(&curs[b], 1);                                        \
    if (r < CAP_B)                                                         \
      pairs[(size_t)b * CAP_B + r] =                                       \
          ((unsigned)((dd) & 127) << 16) | (unsigned)(ss);                 \
  }
      BKT_PUT(d.x, s.x)
      BKT_PUT(d.y, s.y)
      BKT_PUT(d.z, s.z)
      BKT_PUT(d.w, s.w)
#undef BKT_PUT
    }
    return;
  }

  const int lane = threadIdx.x & 63;
  const int m = lane & 15;
  const int quad = lane >> 4;
  const int wv = blockIdx.x * 4 + (threadIdx.x >> 6);
  if (wv >= N_STRIPS) return;
  const int n0 = wv * 16;

  bf16x8 bfrag[4][4];
#pragma unroll
  for (int t = 0; t < 4; ++t) {
    const float* wr = fcw + (size_t)(m + 16 * t) * IN_DIM + quad * 8;
#pragma unroll
    for (int c = 0; c < 4; ++c) {
      float4 lo = *(const float4*)(wr + c * 32);
      float4 hi = *(const float4*)(wr + c * 32 + 4);
      bfrag[t][c] = pack_bf16(lo, hi);
    }
  }

  f32x4 acc[4] = {{0.f, 0.f, 0.f, 0.f}, {0.f, 0.f, 0.f, 0.f},
                  {0.f, 0.f, 0.f, 0.f}, {0.f, 0.f, 0.f, 0.f}};
  const float* ar = feat + (size_t)(n0 + m) * IN_DIM + quad * 8;
#pragma unroll
  for (int c = 0; c < 4; ++c) {
    float4 lo = *(const float4*)(ar + c * 32);
    float4 hi = *(const float4*)(ar + c * 32 + 4);
    const bf16x8 af = pack_bf16(lo, hi);
#pragma unroll
    for (int t = 0; t < 4; ++t)
      acc[t] = __builtin_amdgcn_mfma_f32_16x16x32_bf16(af, bfrag[t][c],
                                                       acc[t], 0, 0, 0);
  }

#pragma unroll
  for (int t = 0; t < 4; ++t)
#pragma unroll
    for (int r = 0; r < 4; ++r)
      z[(size_t)(n0 + quad * 4 + r) * OUT_DIM + m + 16 * t] =
          __float2bfloat16(acc[t][r]);

  float aws[4], awd[4];
#pragma unroll
  for (int t = 0; t < 4; ++t) {
    aws[t] = attnw[m + 16 * t];
    awd[t] = attnw[OUT_DIM + m + 16 * t];
  }
  float ps[4], pd[4];
#pragma unroll
  for (int r = 0; r < 4; ++r) {
    float s = 0.f, d = 0.f;
#pragma unroll
    for (int t = 0; t < 4; ++t) {
      s = fmaf(acc[t][r], aws[t], s);
      d = fmaf(acc[t][r], awd[t], d);
    }
    ps[r] = s;
    pd[r] = d;
  }
#pragma unroll
  for (int off = 1; off < 16; off <<= 1) {
#pragma unroll
    for (int r = 0; r < 4; ++r) {
      ps[r] += __shfl_xor(ps[r], off, 64);
      pd[r] += __shfl_xor(pd[r], off, 64);
    }
  }
  if (m == 0) {
#pragma unroll
    for (int r = 0; r < 4; ++r) {
      asrc[n0 + quad * 4 + r] = ps[r];
      adst[n0 + quad * 4 + r] = pd[r];
    }
  }
}

// ---------------------------------------------------------------------------
// Per-bucket CSR build. Computes its own global base (sum of cnt[0..b),
// L2-hot). (R11 version.)
// ---------------------------------------------------------------------------
__global__ __launch_bounds__(256) void gat_build_csr(
    const unsigned* __restrict__ pairs, const int* __restrict__ cnt,
    int* __restrict__ offsets, int* __restrict__ ssorted) {
  __shared__ int hist[128], exo[128], cur[128], wsum[4];
  const int b = blockIdx.x;
  const int tid = threadIdx.x;

  int ls = 0;
  for (int i = tid; i < b; i += 256) ls += cnt[i * CNT_STRIDE];
#pragma unroll
  for (int off = 32; off; off >>= 1) ls += __shfl_xor(ls, off, 64);
  if ((tid & 63) == 0) wsum[tid >> 6] = ls;
  if (tid < 128) hist[tid] = 0;
  __syncthreads();
  const int base = wsum[0] + wsum[1] + wsum[2] + wsum[3];

  const int c = min(cnt[b * CNT_STRIDE], CAP_B);
  const unsigned* bp = pairs + (size_t)b * CAP_B;
  for (int i = tid; i < c; i += 256) atomicAdd(&hist[bp[i] >> 16], 1);
  __syncthreads();

  if (tid < 128) exo[tid] = hist[tid];
  __syncthreads();
  for (int off = 1; off < 128; off <<= 1) {
    int u = (tid >= off && tid < 128) ? exo[tid - off] : 0;
    __syncthreads();
    if (tid < 128) exo[tid] += u;
    __syncthreads();
  }
  if (tid < 128) {
    const int ex = exo[tid] - hist[tid];
    cur[tid] = ex;
    const int node = b * 128 + tid;
    if (node < N_NODES) offsets[node] = base + ex;
  }
  if (b == NB - 1 && tid == 0) offsets[N_NODES] = base + c;
  __syncthreads();

  for (int i = tid; i < c; i += 256) {
    const unsigned p = bp[i];
    const int r = atomicAdd(&cur[p >> 16], 1);
    ssorted[base + r] = (int)(p & 0xFFFFu);
  }
}

// ---------------------------------------------------------------------------
// Aggregation: one wave per dst node, online softmax, packed s|f16(w)
// shuffle broadcast, uint4 z gather + 8 FMAs per lane per 8 edges, two
// accumulator banks, 3-step cross-subgroup reduction. (R11 version.)
// ---------------------------------------------------------------------------
__global__ __launch_bounds__(256) void gat_agg(
    const __hip_bfloat16* __restrict__ zb, const float* __restrict__ asrc,
    const float* __restrict__ adst, const int* __restrict__ offsets,
    const int* __restrict__ ssorted, float* __restrict__ out) {
  const int lane = threadIdx.x & 63;
  const int j = lane & 7;    // column quad: cols 8j..8j+7
  const int eg = lane >> 3;  // edge subgroup 0..7
  const int node = (blockIdx.x * blockDim.x + threadIdx.x) >> 6;
  if (node >= N_NODES) return;
  const uint4* __restrict__ zp4 = (const uint4*)zb;  // 8 uint4 per 64-col row
  const int o0 = offsets[node];
  const int o1 = offsets[node + 1];
  float4* __restrict__ orow = (float4*)(out + (size_t)node * OUT_DIM);
  if (o0 == o1) {  // no incoming edges: elu(0/1) = 0
    if (eg == 0) {
      const float4 zv = {0.f, 0.f, 0.f, 0.f};
      orow[2 * j] = zv;
      orow[2 * j + 1] = zv;
    }
    return;
  }
  const float ad = adst[node];

  float m = NEG_INF, dsum = 0.f;
  float acca[8] = {0.f, 0.f, 0.f, 0.f, 0.f, 0.f, 0.f, 0.f};
  float accb[8] = {0.f, 0.f, 0.f, 0.f, 0.f, 0.f, 0.f, 0.f};

  for (int base = o0; base < o1; base += 64) {
    const int cnt = min(64, o1 - base);
    int s = 0;
    float ev = NEG_INF;
    if (lane < cnt) {
      s = ssorted[base + lane];
      float v = asrc[s] + ad;
      ev = v > 0.f ? v : NEG_SLOPE * v;
    }
    float cm = ev;
#pragma unroll
    for (int off = 32; off; off >>= 1) cm = fmaxf(cm, __shfl_xor(cm, off, 64));
    const float nm = fmaxf(m, cm);
    const float scale = __expf(m - nm);  // first chunk: exp(-inf) = 0
    dsum *= scale;
#pragma unroll
    for (int c = 0; c < 8; ++c) {
      acca[c] *= scale;
      accb[c] *= scale;
    }
    m = nm;

    const float w = (lane < cnt) ? __expf(ev - m) : 0.f;  // 0 beyond cnt
    dsum += w;
    const unsigned pk =
        (unsigned)s |
        ((unsigned)__half_as_ushort(__float2half(w)) << 16);

    const int ngr = (cnt + 7) >> 3;
    for (int g = 0; g < ngr; g += 2) {
      const unsigned pa = __shfl(pk, 8 * g + eg, 64);
      const int sa = (int)(pa & 0xFFFFu);
      const float wa = __half2float(__ushort_as_half((unsigned short)(pa >> 16)));
      const uint4 ua = zp4[(size_t)sa * 8 + j];
      if (g + 1 < ngr) {
        const unsigned pb = __shfl(pk, 8 * (g + 1) + eg, 64);
        const int sb = (int)(pb & 0xFFFFu);
        const float wb =
            __half2float(__ushort_as_half((unsigned short)(pb >> 16)));
        const uint4 ub = zp4[(size_t)sb * 8 + j];
        accb[0] = fmaf(wb, bflo(ub.x), accb[0]);
        accb[1] = fmaf(wb, bfhi(ub.x), accb[1]);
        accb[2] = fmaf(wb, bflo(ub.y), accb[2]);
        accb[3] = fmaf(wb, bfhi(ub.y), accb[3]);
        accb[4] = fmaf(wb, bflo(ub.z), accb[4]);
        accb[5] = fmaf(wb, bfhi(ub.z), accb[5]);
        accb[6] = fmaf(wb, bflo(ub.w), accb[6]);
        accb[7] = fmaf(wb, bfhi(ub.w), accb[7]);
      }
      acca[0] = fmaf(wa, bflo(ua.x), acca[0]);
      acca[1] = fmaf(wa, bfhi(ua.x), acca[1]);
      acca[2] = fmaf(wa, bflo(ua.y), acca[2]);
      acca[3] = fmaf(wa, bfhi(ua.y), acca[3]);
      acca[4] = fmaf(wa, bflo(ua.z), acca[4]);
      acca[5] = fmaf(wa, bfhi(ua.z), acca[5]);
      acca[6] = fmaf(wa, bflo(ua.w), acca[6]);
      acca[7] = fmaf(wa, bfhi(ua.w), acca[7]);
    }
  }

  float acc[8];
#pragma unroll
  for (int c = 0; c < 8; ++c) acc[c] = acca[c] + accb[c];
#pragma unroll
  for (int off = 8; off < 64; off <<= 1)
#pragma unroll
    for (int c = 0; c < 8; ++c) acc[c] += __shfl_xor(acc[c], off, 64);
#pragma unroll
  for (int off = 32; off; off >>= 1) dsum += __shfl_xor(dsum, off, 64);

  if (eg == 0) {
    const float inv = 1.f / (dsum > 0.f ? dsum : 1.f);
    float4 r0, r1;
    float h;
    h = acc[0] * inv; r0.x = h > 0.f ? h : expm1f(h);
    h = acc[1] * inv; r0.y = h > 0.f ? h : expm1f(h);
    h = acc[2] * inv; r0.z = h > 0.f ? h : expm1f(h);
    h = acc[3] * inv; r0.w = h > 0.f ? h : expm1f(h);
    h = acc[4] * inv; r1.x = h > 0.f ? h : expm1f(h);
    h = acc[5] * inv; r1.y = h > 0.f ? h : expm1f(h);
    h = acc[6] * inv; r1.z = h > 0.f ? h : expm1f(h);
    h = acc[7] * inv; r1.w = h > 0.f ? h : expm1f(h);
    orow[2 * j] = r0;
    orow[2 * j + 1] = r1;
  }
}

// ---------------------------------------------------------------------------
extern "C" void kernel_launch(void* const* d_in, const int* in_sizes, int n_in,
                              void* d_out, int out_size, void* d_ws, size_t ws_size,
                              hipStream_t stream) {
  const float* feat  = (const float*)d_in[0];
  const float* fcw   = (const float*)d_in[1];
  const float* attnw = (const float*)d_in[2];
  const int* src     = (const int*)d_in[3];
  const int* dst     = (const int*)d_in[4];
  float* out = (float*)d_out;

  char* ws = (char*)d_ws;
  __hip_bfloat16* z = (__hip_bfloat16*)ws;
  ws += (size_t)N_NODES * OUT_DIM * sizeof(__hip_bfloat16);  // 6.4 MB
  float* asrc = (float*)ws;   ws += (size_t)N_NODES * sizeof(float);
  float* adst = (float*)ws;   ws += (size_t)N_NODES * sizeof(float);
  int* cnt = (int*)ws;        ws += (size_t)NB * CNT_STRIDE * sizeof(int);  // 25 KB
  int* offsets = (int*)ws;    ws += (size_t)(N_NODES + 4) * sizeof(int);
  unsigned* pairs = (unsigned*)ws; ws += (size_t)NB * CAP_B * sizeof(unsigned);  // 4.8 MB
  int* ssorted = (int*)ws;    ws += (size_t)N_EDGES * sizeof(int);               // 3.2 MB

  hipMemsetAsync(cnt, 0, (size_t)NB * CNT_STRIDE * sizeof(int), stream);

  gat_z_bucket<<<Z_BLOCKS + EB, 256, 0, stream>>>(
      feat, fcw, attnw, z, asrc, adst, src, dst, cnt, pairs);
  gat_build_csr<<<NB, 256, 0, stream>>>(pairs, cnt, offsets, ssorted);
  gat_agg<<<(N_NODES * 64 + 255) / 256, 256, 0, stream>>>(z, asrc, adst,
                                                          offsets, ssorted, out);
}